// Round 7
// baseline (226.254 us; speedup 1.0000x reference)
//
#include <hip/hip_runtime.h>
#include <hip/hip_bf16.h>

#define NN 16384

typedef __attribute__((ext_vector_type(4))) float  f32x4;
typedef __attribute__((ext_vector_type(8))) short  s16x8;
typedef __attribute__((ext_vector_type(4))) short  s16x4;

__device__ inline short bf16_of(float f) {
    return __builtin_bit_cast(short, __float2bfloat16(f));
}

// Kernel 1: HpT[c][m] (bf16), c = b*16+g.  h[b,m,g] = sum_f x[b,m,f]*ker[m,f,g]
__global__ void fuse_h(const float* __restrict__ x, const float* __restrict__ ker,
                       __hip_bfloat16* __restrict__ hpt) {
    int tid = blockIdx.x * 256 + threadIdx.x;
    int g = tid & 15;
    int m = tid >> 4;            // 0..16383
    const float* xb0 = x + m * 16;
    const float* xb1 = x + NN * 16 + m * 16;
    const float* kp  = ker + m * 256 + g;
    float h0 = 0.f, h1 = 0.f;
#pragma unroll
    for (int f = 0; f < 16; ++f) {
        float kk = kp[f * 16];
        h0 += xb0[f] * kk;
        h1 += xb1[f] * kk;
    }
    hpt[g * NN + m]        = __float2bfloat16(h0);
    hpt[(16 + g) * NN + m] = __float2bfloat16(h1);
}

// Kernel 2: out[b,n,g] = sum_m A[n,m]*Hp[m,c] + bias[n,g]
// 1024 single-wave blocks x 16 rows x FULL 16K k (no K-split): each A row has
// exactly ONE concurrent walker (streams 65K -> 16K), no partials/reduce.
// Per-block k-phase stagger decorrelates machine-wide DRAM bank access.
// Staging path identical to R6: K-step 256, 1KB single-row bursts, wave-private
// 8KB LDS tile, XOR swizzle, zero barriers, B-before-A issue order.
__global__ __launch_bounds__(64, 1) void gcn_main(
        const float* __restrict__ A,
        const __hip_bfloat16* __restrict__ hpt,
        const float* __restrict__ bias,
        float* __restrict__ out) {
    __shared__ __attribute__((aligned(16))) char lds[8192];

    const int lane = threadIdx.x;        // 0..63 (single wave)
    const int n0   = blockIdx.x * 16;
    const int row  = lane & 15;          // MFMA fragment row / D col (=g)
    const int kg   = lane >> 4;          // 0..3
    const int phase = blockIdx.x & 63;   // k-phase stagger (reduction: order free)

    f32x4 acc0 = {0.f, 0.f, 0.f, 0.f};
    f32x4 acc1 = {0.f, 0.f, 0.f, 0.f};
    f32x4 st[16];

    const float* abase = A + (size_t)n0 * NN;
    const __hip_bfloat16* b0base = hpt + row * NN + kg * 8;  // c-tile 0 (b=0)
    const __hip_bfloat16* b1base = b0base + 16 * NN;         // c-tile 1 (b=1)

    // ---- prologue: stage slab `phase` (16 x 1KB single-row bursts) ----
#pragma unroll
    for (int r = 0; r < 16; ++r)
        st[r] = __builtin_nontemporal_load(
                    (const f32x4*)(abase + (size_t)r * NN + phase * 256 + lane * 4));
#pragma unroll
    for (int r = 0; r < 16; ++r) {
        int byte = (r * 512 + lane * 8) ^ ((r & 7) << 4);
        s16x4 v;
        v[0] = bf16_of(st[r][0]); v[1] = bf16_of(st[r][1]);
        v[2] = bf16_of(st[r][2]); v[3] = bf16_of(st[r][3]);
        *(s16x4*)(lds + byte) = v;
    }

#pragma unroll 1
    for (int t = 0; t < 64; ++t) {
        const int s  = (phase + t) & 63;       // current slab (resident in LDS)
        const int sn = (phase + t + 1) & 63;   // next slab
        // B half-0 FIRST (L2-resident): its counted vmcnt wait must not drain
        // the A prefetch issued below (vmcnt is in-order).
        s16x8 bb0[4], bb1[4];
#pragma unroll
        for (int j = 0; j < 4; ++j) {
            bb0[j] = *(const s16x8*)(b0base + s * 256 + j * 32);
            bb1[j] = *(const s16x8*)(b1base + s * 256 + j * 32);
        }
        // A prefetch for next slab (guarded: no re-reads)
        if (t < 63) {
            const float* ap = abase + sn * 256 + lane * 4;
#pragma unroll
            for (int r = 0; r < 16; ++r)
                st[r] = __builtin_nontemporal_load(
                            (const f32x4*)(ap + (size_t)r * NN));
        }
        // consume half-0 of current slab from LDS (waits only on B half-0)
#pragma unroll
        for (int j = 0; j < 4; ++j) {
            int byte = (row * 512 + j * 64 + kg * 16) ^ ((row & 7) << 4);
            s16x8 af = *(const s16x8*)(lds + byte);
            acc0 = __builtin_amdgcn_mfma_f32_16x16x32_bf16(af, bb0[j], acc0, 0, 0, 0);
            acc1 = __builtin_amdgcn_mfma_f32_16x16x32_bf16(af, bb1[j], acc1, 0, 0, 0);
        }
        // B half-1 (issued after A; its consume drains A, which the LDS write
        // below needs anyway -- single stall point per iteration)
        s16x8 cb0[4], cb1[4];
#pragma unroll
        for (int j = 0; j < 4; ++j) {
            cb0[j] = *(const s16x8*)(b0base + s * 256 + 128 + j * 32);
            cb1[j] = *(const s16x8*)(b1base + s * 256 + 128 + j * 32);
        }
#pragma unroll
        for (int j = 0; j < 4; ++j) {
            int byte = (row * 512 + 256 + j * 64 + kg * 16) ^ ((row & 7) << 4);
            s16x8 af = *(const s16x8*)(lds + byte);
            acc0 = __builtin_amdgcn_mfma_f32_16x16x32_bf16(af, cb0[j], acc0, 0, 0, 0);
            acc1 = __builtin_amdgcn_mfma_f32_16x16x32_bf16(af, cb1[j], acc1, 0, 0, 0);
        }
        // convert + write next slab (A drained; wave-private, no barrier)
        if (t < 63) {
#pragma unroll
            for (int r = 0; r < 16; ++r) {
                int byte = (r * 512 + lane * 8) ^ ((r & 7) << 4);
                s16x4 v;
                v[0] = bf16_of(st[r][0]); v[1] = bf16_of(st[r][1]);
                v[2] = bf16_of(st[r][2]); v[3] = bf16_of(st[r][3]);
                *(s16x4*)(lds + byte) = v;
            }
        }
    }

    // Epilogue: D mapping col = lane&15 (=g), row = kg*4 + i (A-row offset).
    // Final result -> out directly, bias fused (no partials, no reduce).
#pragma unroll
    for (int i = 0; i < 4; ++i) {
        int n = n0 + kg * 4 + i;
        float bv = bias[n * 16 + row];
        out[(size_t)0 * (NN * 16) + n * 16 + row] = acc0[i] + bv;
        out[(size_t)1 * (NN * 16) + n * 16 + row] = acc1[i] + bv;
    }
}

extern "C" void kernel_launch(void* const* d_in, const int* in_sizes, int n_in,
                              void* d_out, int out_size, void* d_ws, size_t ws_size,
                              hipStream_t stream) {
    const float* x    = (const float*)d_in[0];
    const float* A    = (const float*)d_in[1];
    const float* ker  = (const float*)d_in[2];
    const float* bias = (const float*)d_in[3];
    float* out = (float*)d_out;
    __hip_bfloat16* hpt = (__hip_bfloat16*)d_ws;   // 32*16384*2B = 1 MB

    fuse_h<<<dim3(NN * 16 / 256), dim3(256), 0, stream>>>(x, ker, hpt);
    gcn_main<<<dim3(NN / 16), dim3(64), 0, stream>>>(A, hpt, bias, out);
}